// Round 4
// baseline (7142.157 us; speedup 1.0000x reference)
//
#include <hip/hip_runtime.h>

#define V 256
#define H 2048
#define A 512
#define S 512
#define NBLK 128
#define NTHR 512

typedef float f32x4 __attribute__((ext_vector_type(4)));

// ---- payload+epoch chunk: (v0, v1, pad, tag) in one 16B coherent store ----
__device__ __forceinline__ void st_chunk(float* p, float x, float y, int tag) {
    f32x4 v; v.x = x; v.y = y; v.z = 0.f; v.w = __int_as_float(tag);
    asm volatile("global_store_dwordx4 %0, %1, off sc0 sc1" :: "v"(p), "v"(v) : "memory");
}
__device__ __forceinline__ f32x4 poll1(const float* p, int tag) {
    f32x4 r;
    for (;;) {
        asm volatile("global_load_dwordx4 %0, %1, off sc0 sc1\n\ts_waitcnt vmcnt(0)"
                     : "=v"(r) : "v"(p) : "memory");
        if (__float_as_int(r.w) == tag) return r;
    }
}
__device__ __forceinline__ void poll2(const float* p0, const float* p1, int tag,
                                      f32x4& a, f32x4& b) {
    for (;;) {
        asm volatile("global_load_dwordx4 %0, %2, off sc0 sc1\n\t"
                     "global_load_dwordx4 %1, %3, off sc0 sc1\n\t"
                     "s_waitcnt vmcnt(0)"
                     : "=v"(a), "=v"(b) : "v"(p0), "v"(p1) : "memory");
        if (__float_as_int(a.w) == tag && __float_as_int(b.w) == tag) return;
    }
}

__global__ void init_ex(float* p, int n) {
    int i = blockIdx.x * blockDim.x + threadIdx.x;
    if (i < n) p[i] = 0.f;
}

// ---------------- generic NT GEMM (unchanged) ----------------
__global__ __launch_bounds__(256) void gemm_nt(
    const float* __restrict__ Amat, int lda,
    const float* __restrict__ Bmat, int ldb,
    float* __restrict__ C, int ldc,
    const float* __restrict__ bias, int M, int N, int K)
{
    __shared__ float As[16][68];
    __shared__ float Bs[16][68];
    const int tid = threadIdx.x;
    const int tx = tid & 15;
    const int ty = tid >> 4;
    const int m0 = blockIdx.y * 64;
    const int n0 = blockIdx.x * 64;
    const int lr = tid >> 2;
    const int lk = (tid & 3) * 4;

    float acc[4][4] = {};
    for (int k0 = 0; k0 < K; k0 += 16) {
        float4 av = *(const float4*)(Amat + (size_t)(m0 + lr) * lda + k0 + lk);
        float4 bv = *(const float4*)(Bmat + (size_t)(n0 + lr) * ldb + k0 + lk);
        __syncthreads();
        As[lk+0][lr] = av.x; As[lk+1][lr] = av.y; As[lk+2][lr] = av.z; As[lk+3][lr] = av.w;
        Bs[lk+0][lr] = bv.x; Bs[lk+1][lr] = bv.y; Bs[lk+2][lr] = bv.z; Bs[lk+3][lr] = bv.w;
        __syncthreads();
        #pragma unroll
        for (int k = 0; k < 16; ++k) {
            float a4[4], b4[4];
            #pragma unroll
            for (int i = 0; i < 4; ++i) a4[i] = As[k][ty*4+i];
            #pragma unroll
            for (int j = 0; j < 4; ++j) b4[j] = Bs[k][tx*4+j];
            #pragma unroll
            for (int i = 0; i < 4; ++i)
                #pragma unroll
                for (int j = 0; j < 4; ++j) acc[i][j] += a4[i] * b4[j];
        }
    }
    #pragma unroll
    for (int i = 0; i < 4; ++i) {
        const int m = m0 + ty*4 + i;
        #pragma unroll
        for (int j = 0; j < 4; ++j) {
            const int n = n0 + tx*4 + j;
            float v = acc[i][j];
            if (bias) v += bias[n];
            C[(size_t)m * ldc + n] = v;
        }
    }
}

// ---------------- persistent encoder scan: payload-polling, no barriers ----------------
__global__ __launch_bounds__(NTHR, 2) void enc_scan(
    const float* __restrict__ W_enc, const float* __restrict__ accx,
    float* __restrict__ states, float* __restrict__ hex)
{
    __shared__ __align__(16) float hs[2][H];
    const int tid = threadIdx.x;
    const int wid = tid >> 6, lane = tid & 63;
    const int w   = blockIdx.x * 8 + wid;     // 0..1023, wave owns rows 2w,2w+1
    const int r0  = 2*w, r1 = r0 + 1;

    f32x4 we0[8], we1[8];
    #pragma unroll
    for (int k = 0; k < 8; ++k) {
        we0[k] = *(const f32x4*)(W_enc + (size_t)r0*(V+H) + V + 4*(lane + 64*k));
        we1[k] = *(const f32x4*)(W_enc + (size_t)r1*(V+H) + V + 4*(lane + 64*k));
    }

    // t = 0: h = tanh(accx)
    if (lane == 0) {
        float h0 = tanhf(accx[r0]), h1 = tanhf(accx[r1]);
        states[r0] = h0; states[r1] = h1;
        st_chunk(hex + 4*w, h0, h1, 1);       // buf 0, tag 1
    }

    for (int t = 1; t < S; ++t) {
        // poll h_{t-1}: chunks 2*tid, 2*tid+1 in buf (t-1)&1, tag t
        f32x4 ca, cb;
        const float* hb = hex + ((t-1)&1)*4096;
        poll2(hb + 8*tid, hb + 8*tid + 4, t, ca, cb);
        float* dst = hs[t&1];
        dst[4*tid+0] = ca.x; dst[4*tid+1] = ca.y;
        dst[4*tid+2] = cb.x; dst[4*tid+3] = cb.y;
        __syncthreads();

        const f32x4* h4 = (const f32x4*)hs[t&1];
        float a0 = 0.f, a1 = 0.f;
        #pragma unroll
        for (int k = 0; k < 8; ++k) {
            f32x4 hv = h4[lane + 64*k];
            a0 += we0[k].x*hv.x + we0[k].y*hv.y + we0[k].z*hv.z + we0[k].w*hv.w;
            a1 += we1[k].x*hv.x + we1[k].y*hv.y + we1[k].z*hv.z + we1[k].w*hv.w;
        }
        #pragma unroll
        for (int off = 32; off; off >>= 1) { a0 += __shfl_down(a0, off); a1 += __shfl_down(a1, off); }
        if (lane == 0) {
            float h0 = tanhf(a0 + accx[(size_t)t*H + r0]);
            float h1 = tanhf(a1 + accx[(size_t)t*H + r1]);
            states[(size_t)t*H + r0] = h0; states[(size_t)t*H + r1] = h1;
            st_chunk(hex + (t&1)*4096 + 4*w, h0, h1, t+1);
        }
    }
}

// ---------------- persistent decoder scan: 3 one-hop exchanges/step ----------------
__global__ __launch_bounds__(NTHR, 2) void dec_scan(
    const float* __restrict__ Wa_dec, const float* __restrict__ W_dec,
    const float* __restrict__ enc_proj, const float* __restrict__ v_a,
    const float* __restrict__ WcT, const float* __restrict__ accx,
    const float* __restrict__ enc_states, float* __restrict__ h_dec,
    float* __restrict__ hexd, float* __restrict__ dpex, float* __restrict__ eex)
{
    __shared__ __align__(16) float hs[H];
    __shared__ __align__(16) float ps[A];
    __shared__ __align__(16) float es[S];
    __shared__ float zred[8];
    const int tid = threadIdx.x;
    const int wid = tid >> 6, lane = tid & 63;
    const int w   = blockIdx.x * 8 + wid;     // 0..1023
    const int r0  = 2*w, r1 = r0 + 1;
    const bool attn_blk = (blockIdx.x < 64);  // waves with w<512 own a=w and s=w

    f32x4 wh0[8], wh1[8], wa[8], wc0[2], wc1[2], ep[2], va[2];
    #pragma unroll
    for (int k = 0; k < 8; ++k) {
        wh0[k] = *(const f32x4*)(W_dec + (size_t)r0*(V+2*H) + V + H + 4*(lane + 64*k));
        wh1[k] = *(const f32x4*)(W_dec + (size_t)r1*(V+2*H) + V + H + 4*(lane + 64*k));
        wa[k]  = (f32x4)(0.f);
    }
    #pragma unroll
    for (int k = 0; k < 2; ++k) {
        wc0[k] = *(const f32x4*)(WcT + (size_t)r0*S + 4*(lane + 64*k));
        wc1[k] = *(const f32x4*)(WcT + (size_t)r1*S + 4*(lane + 64*k));
        ep[k] = (f32x4)(0.f); va[k] = (f32x4)(0.f);
    }
    if (attn_blk) {
        #pragma unroll
        for (int k = 0; k < 8; ++k)
            wa[k] = *(const f32x4*)(Wa_dec + (size_t)w*H + 4*(lane + 64*k));
        #pragma unroll
        for (int k = 0; k < 2; ++k) {
            ep[k] = *(const f32x4*)(enc_proj + (size_t)w*A + 4*(lane + 64*k));
            va[k] = *(const f32x4*)(v_a + 4*(lane + 64*k));
        }
    }
    const f32x4* hs4 = (const f32x4*)hs;
    const f32x4* ps4 = (const f32x4*)ps;
    const f32x4* es4 = (const f32x4*)es;

    for (int t = 0; t < S; ++t) {
        // ---- A: stage h_{t-1} ----
        if (t == 0) {
            ((f32x4*)hs)[tid] = ((const f32x4*)(enc_states + (size_t)(S-1)*H))[tid];
        } else {
            f32x4 ca, cb;
            const float* hb = hexd + ((t-1)&1)*4096;
            poll2(hb + 8*tid, hb + 8*tid + 4, t, ca, cb);
            hs[4*tid+0] = ca.x; hs[4*tid+1] = ca.y;
            hs[4*tid+2] = cb.x; hs[4*tid+3] = cb.y;
        }
        __syncthreads();                                   // sync1

        // ---- B: publish dec_proj ASAP, then heavy W_h dot ----
        if (attn_blk) {
            float aP = 0.f;
            #pragma unroll
            for (int k = 0; k < 8; ++k) {
                f32x4 hv = hs4[lane + 64*k];
                aP += wa[k].x*hv.x + wa[k].y*hv.y + wa[k].z*hv.z + wa[k].w*hv.w;
            }
            #pragma unroll
            for (int off = 32; off; off >>= 1) aP += __shfl_down(aP, off);
            if (lane == 0) st_chunk(dpex + (t&1)*2048 + 4*w, aP, 0.f, t+1);
        }
        float aH0 = 0.f, aH1 = 0.f;
        #pragma unroll
        for (int k = 0; k < 8; ++k) {
            f32x4 hv = hs4[lane + 64*k];
            aH0 += wh0[k].x*hv.x + wh0[k].y*hv.y + wh0[k].z*hv.z + wh0[k].w*hv.w;
            aH1 += wh1[k].x*hv.x + wh1[k].y*hv.y + wh1[k].z*hv.z + wh1[k].w*hv.w;
        }
        #pragma unroll
        for (int off = 32; off; off >>= 1) { aH0 += __shfl_down(aH0, off); aH1 += __shfl_down(aH1, off); }

        // ---- C: attention blocks: dp -> e ----
        if (attn_blk) {
            f32x4 c = poll1(dpex + (t&1)*2048 + 4*tid, t+1);
            ps[tid] = c.x;
            __syncthreads();                               // sync2 (attn blocks only)
            float e_ = 0.f;
            #pragma unroll
            for (int k = 0; k < 2; ++k) {
                f32x4 p = ps4[lane + 64*k];
                e_ += va[k].x*tanhf(ep[k].x + p.x) + va[k].y*tanhf(ep[k].y + p.y)
                    + va[k].z*tanhf(ep[k].z + p.z) + va[k].w*tanhf(ep[k].w + p.w);
            }
            #pragma unroll
            for (int off = 32; off; off >>= 1) e_ += __shfl_down(e_, off);
            if (lane == 0) st_chunk(eex + (t&1)*2048 + 4*w, expf(e_), 0.f, t+1);
        }

        // ---- D: all blocks: poll e ----
        {
            f32x4 c = poll1(eex + (t&1)*2048 + 4*tid, t+1);
            es[tid] = c.x;
        }
        __syncthreads();                                   // syncD

        // ---- E: Z, ctx, h_new ----
        float z = es[tid];
        #pragma unroll
        for (int off = 32; off; off >>= 1) z += __shfl_down(z, off);
        if (lane == 0) zred[wid] = z;
        __syncthreads();                                   // syncZ
        const float Z = zred[0]+zred[1]+zred[2]+zred[3]+zred[4]+zred[5]+zred[6]+zred[7];

        float c0 = 0.f, c1 = 0.f;
        #pragma unroll
        for (int k = 0; k < 2; ++k) {
            f32x4 ev = es4[lane + 64*k];
            c0 += wc0[k].x*ev.x + wc0[k].y*ev.y + wc0[k].z*ev.z + wc0[k].w*ev.w;
            c1 += wc1[k].x*ev.x + wc1[k].y*ev.y + wc1[k].z*ev.z + wc1[k].w*ev.w;
        }
        #pragma unroll
        for (int off = 32; off; off >>= 1) { c0 += __shfl_down(c0, off); c1 += __shfl_down(c1, off); }
        if (lane == 0) {
            const float Zi = 1.f / Z;
            float h0 = tanhf(accx[(size_t)t*H + r0] + aH0 + c0*Zi);
            float h1 = tanhf(accx[(size_t)t*H + r1] + aH1 + c1*Zi);
            h_dec[(size_t)t*H + r0] = h0; h_dec[(size_t)t*H + r1] = h1;
            st_chunk(hexd + (t&1)*4096 + 4*w, h0, h1, t+1);
        }
    }
}

extern "C" void kernel_launch(void* const* d_in, const int* in_sizes, int n_in,
                              void* d_out, int out_size, void* d_ws, size_t ws_size,
                              hipStream_t stream) {
    const float* x_enc  = (const float*)d_in[0];
    const float* x_dec  = (const float*)d_in[1];
    const float* W_enc  = (const float*)d_in[2];
    const float* b_enc  = (const float*)d_in[3];
    const float* Wa_enc = (const float*)d_in[4];
    const float* Wa_dec = (const float*)d_in[5];
    const float* v_a    = (const float*)d_in[6];
    const float* W_dec  = (const float*)d_in[7];
    const float* b_dec  = (const float*)d_in[8];
    const float* W_out  = (const float*)d_in[9];
    const float* b_out  = (const float*)d_in[10];
    float* out = (float*)d_out;

    float* ws         = (float*)d_ws;
    float* accx_enc   = ws;                          // S*H
    float* enc_states = accx_enc + (size_t)S*H;      // S*H
    float* enc_proj   = enc_states + (size_t)S*H;    // S*A
    float* WcT        = enc_proj + (size_t)S*A;      // H*S
    float* accx_dec   = WcT + (size_t)H*S;           // S*H
    float* h_dec      = accx_dec + (size_t)S*H;      // S*H
    float* hex_e      = h_dec + (size_t)S*H;         // 2*1024*4 = 8192
    float* hex_d      = hex_e + 8192;                // 8192
    float* dp_ex      = hex_d + 8192;                // 2*512*4 = 4096
    float* e_ex       = dp_ex + 4096;                // 4096
    const int n_ex = 8192 + 8192 + 4096 + 4096;      // 24576 floats to zero

    dim3 b256(256);

    init_ex<<<dim3((n_ex + 255)/256), b256, 0, stream>>>(hex_e, n_ex);

    // accx_enc = x_enc @ W_enc[:, :V].T + b_enc
    gemm_nt<<<dim3(H/64, S/64), b256, 0, stream>>>(x_enc, V, W_enc, V+H, accx_enc, H, b_enc, S, H, V);
    // accx_dec = x_dec @ W_dec[:, :V].T + b_dec
    gemm_nt<<<dim3(H/64, S/64), b256, 0, stream>>>(x_dec, V, W_dec, V+2*H, accx_dec, H, b_dec, S, H, V);

    // encoder scan (cooperative, persistent, payload-polling)
    {
        const float* We = W_enc; const float* ax = accx_enc; float* st = enc_states; float* hx = hex_e;
        void* args[] = { &We, &ax, &st, &hx };
        hipLaunchCooperativeKernel((void*)enc_scan, dim3(NBLK), dim3(NTHR), args, 0, stream);
    }

    // enc_proj = enc_states @ Wa_enc.T
    gemm_nt<<<dim3(A/64, S/64), b256, 0, stream>>>(enc_states, H, Wa_enc, H, enc_proj, A, nullptr, S, A, H);
    // WcT[i][s] = W_c[i]·enc_states[s]
    gemm_nt<<<dim3(S/64, H/64), b256, 0, stream>>>(W_dec + V, V+2*H, enc_states, H, WcT, S, nullptr, H, S, H);

    // decoder scan (cooperative, persistent, payload-polling)
    {
        const float* wa = Wa_dec; const float* wd = W_dec; const float* epj = enc_proj;
        const float* vv = v_a; const float* wc = WcT; const float* ax = accx_dec;
        const float* est = enc_states; float* hd = h_dec;
        float* hx = hex_d; float* dx = dp_ex; float* ex = e_ex;
        void* args[] = { &wa, &wd, &epj, &vv, &wc, &ax, &est, &hd, &hx, &dx, &ex };
        hipLaunchCooperativeKernel((void*)dec_scan, dim3(NBLK), dim3(NTHR), args, 0, stream);
    }

    // logits = h_dec @ W_out.T + b_out
    gemm_nt<<<dim3(V/64, S/64), b256, 0, stream>>>(h_dec, H, W_out, H, out, V, b_out, S, V, H);
}

// Round 5
// 6103.030 us; speedup vs baseline: 1.1703x; 1.1703x over previous
//
#include <hip/hip_runtime.h>

#define V 256
#define H 2048
#define A 512
#define S 512
#define NBLK 128
#define NTHR 512
#define CH 64   // floats per exchange chunk slot (256B) -> spread across HBM/IC channels

typedef float f32x4 __attribute__((ext_vector_type(4)));

// ---- payload+epoch chunk: (v0, v1, pad, tag) in one 16B coherent store ----
__device__ __forceinline__ void st_chunk(float* p, float x, float y, int tag) {
    f32x4 v; v.x = x; v.y = y; v.z = 0.f; v.w = __int_as_float(tag);
    asm volatile("global_store_dwordx4 %0, %1, off sc0 sc1" :: "v"(p), "v"(v) : "memory");
}
__device__ __forceinline__ f32x4 poll1(const float* p, int tag) {
    f32x4 r;
    for (;;) {
        asm volatile("global_load_dwordx4 %0, %1, off sc0 sc1\n\ts_waitcnt vmcnt(0)"
                     : "=&v"(r) : "v"(p) : "memory");
        if (__float_as_int(r.w) == tag) return r;
    }
}
__device__ __forceinline__ void poll2(const float* p0, const float* p1, int tag,
                                      f32x4& a, f32x4& b) {
    for (;;) {
        asm volatile("global_load_dwordx4 %0, %2, off sc0 sc1\n\t"
                     "global_load_dwordx4 %1, %3, off sc0 sc1\n\t"
                     "s_waitcnt vmcnt(0)"
                     : "=&v"(a), "=&v"(b) : "v"(p0), "v"(p1) : "memory");
        if (__float_as_int(a.w) == tag && __float_as_int(b.w) == tag) return;
    }
}

__global__ void init_ex(float* p, int n) {
    int i = blockIdx.x * blockDim.x + threadIdx.x;
    if (i < n) p[i] = 0.f;
}

// ---------------- generic NT GEMM (unchanged) ----------------
__global__ __launch_bounds__(256) void gemm_nt(
    const float* __restrict__ Amat, int lda,
    const float* __restrict__ Bmat, int ldb,
    float* __restrict__ C, int ldc,
    const float* __restrict__ bias, int M, int N, int K)
{
    __shared__ float As[16][68];
    __shared__ float Bs[16][68];
    const int tid = threadIdx.x;
    const int tx = tid & 15;
    const int ty = tid >> 4;
    const int m0 = blockIdx.y * 64;
    const int n0 = blockIdx.x * 64;
    const int lr = tid >> 2;
    const int lk = (tid & 3) * 4;

    float acc[4][4] = {};
    for (int k0 = 0; k0 < K; k0 += 16) {
        float4 av = *(const float4*)(Amat + (size_t)(m0 + lr) * lda + k0 + lk);
        float4 bv = *(const float4*)(Bmat + (size_t)(n0 + lr) * ldb + k0 + lk);
        __syncthreads();
        As[lk+0][lr] = av.x; As[lk+1][lr] = av.y; As[lk+2][lr] = av.z; As[lk+3][lr] = av.w;
        Bs[lk+0][lr] = bv.x; Bs[lk+1][lr] = bv.y; Bs[lk+2][lr] = bv.z; Bs[lk+3][lr] = bv.w;
        __syncthreads();
        #pragma unroll
        for (int k = 0; k < 16; ++k) {
            float a4[4], b4[4];
            #pragma unroll
            for (int i = 0; i < 4; ++i) a4[i] = As[k][ty*4+i];
            #pragma unroll
            for (int j = 0; j < 4; ++j) b4[j] = Bs[k][tx*4+j];
            #pragma unroll
            for (int i = 0; i < 4; ++i)
                #pragma unroll
                for (int j = 0; j < 4; ++j) acc[i][j] += a4[i] * b4[j];
        }
    }
    #pragma unroll
    for (int i = 0; i < 4; ++i) {
        const int m = m0 + ty*4 + i;
        #pragma unroll
        for (int j = 0; j < 4; ++j) {
            const int n = n0 + tx*4 + j;
            float v = acc[i][j];
            if (bias) v += bias[n];
            C[(size_t)m * ldc + n] = v;
        }
    }
}

// ---------------- persistent encoder scan: payload-polling, channel-spread chunks ----------------
__global__ __launch_bounds__(NTHR, 2) void enc_scan(
    const float* __restrict__ W_enc, const float* __restrict__ accx,
    float* __restrict__ states, float* __restrict__ hex)
{
    __shared__ __align__(16) float hs[2][H];
    const int tid = threadIdx.x;
    const int wid = tid >> 6, lane = tid & 63;
    const int w   = blockIdx.x * 8 + wid;     // 0..1023, wave owns rows 2w,2w+1
    const int r0  = 2*w, r1 = r0 + 1;

    f32x4 we0[8], we1[8];
    #pragma unroll
    for (int k = 0; k < 8; ++k) {
        we0[k] = *(const f32x4*)(W_enc + (size_t)r0*(V+H) + V + 4*(lane + 64*k));
        we1[k] = *(const f32x4*)(W_enc + (size_t)r1*(V+H) + V + 4*(lane + 64*k));
    }

    // t = 0: h = tanh(accx)
    if (lane == 0) {
        float h0 = tanhf(accx[r0]), h1 = tanhf(accx[r1]);
        states[r0] = h0; states[r1] = h1;
        st_chunk(hex + w*CH, h0, h1, 1);      // buf 0, tag 1
    }

    for (int t = 1; t < S; ++t) {
        // prefetch this step's accx (L2 hit) so publish isn't gated on it
        float ax0 = 0.f, ax1 = 0.f;
        if (lane == 0) {
            ax0 = accx[(size_t)t*H + r0];
            ax1 = accx[(size_t)t*H + r1];
        }
        // poll h_{t-1}: chunks 2*tid, 2*tid+1 in buf (t-1)&1, tag t
        f32x4 ca, cb;
        const float* hb = hex + ((t-1)&1)*(1024*CH);
        poll2(hb + (2*tid)*CH, hb + (2*tid+1)*CH, t, ca, cb);
        float* dst = hs[t&1];
        dst[4*tid+0] = ca.x; dst[4*tid+1] = ca.y;
        dst[4*tid+2] = cb.x; dst[4*tid+3] = cb.y;
        __syncthreads();

        const f32x4* h4 = (const f32x4*)hs[t&1];
        float a0 = 0.f, a1 = 0.f;
        #pragma unroll
        for (int k = 0; k < 8; ++k) {
            f32x4 hv = h4[lane + 64*k];
            a0 += we0[k].x*hv.x + we0[k].y*hv.y + we0[k].z*hv.z + we0[k].w*hv.w;
            a1 += we1[k].x*hv.x + we1[k].y*hv.y + we1[k].z*hv.z + we1[k].w*hv.w;
        }
        #pragma unroll
        for (int off = 32; off; off >>= 1) { a0 += __shfl_down(a0, off); a1 += __shfl_down(a1, off); }
        if (lane == 0) {
            float h0 = tanhf(a0 + ax0);
            float h1 = tanhf(a1 + ax1);
            states[(size_t)t*H + r0] = h0; states[(size_t)t*H + r1] = h1;
            st_chunk(hex + (t&1)*(1024*CH) + w*CH, h0, h1, t+1);
        }
    }
}

// ---------------- persistent decoder scan: 3 one-hop exchanges/step, channel-spread ----------------
__global__ __launch_bounds__(NTHR, 2) void dec_scan(
    const float* __restrict__ Wa_dec, const float* __restrict__ W_dec,
    const float* __restrict__ enc_proj, const float* __restrict__ v_a,
    const float* __restrict__ WcT, const float* __restrict__ accx,
    const float* __restrict__ enc_states, float* __restrict__ h_dec,
    float* __restrict__ hexd, float* __restrict__ dpex, float* __restrict__ eex)
{
    __shared__ __align__(16) float hs[H];
    __shared__ __align__(16) float ps[A];
    __shared__ __align__(16) float es[S];
    __shared__ float zred[8];
    const int tid = threadIdx.x;
    const int wid = tid >> 6, lane = tid & 63;
    const int w   = blockIdx.x * 8 + wid;     // 0..1023
    const int r0  = 2*w, r1 = r0 + 1;
    const bool attn_blk = (blockIdx.x < 64);  // waves with w<512 own a=w and s=w

    f32x4 wh0[8], wh1[8], wa[8], wc0[2], wc1[2], ep[2], va[2];
    #pragma unroll
    for (int k = 0; k < 8; ++k) {
        wh0[k] = *(const f32x4*)(W_dec + (size_t)r0*(V+2*H) + V + H + 4*(lane + 64*k));
        wh1[k] = *(const f32x4*)(W_dec + (size_t)r1*(V+2*H) + V + H + 4*(lane + 64*k));
        wa[k]  = (f32x4)(0.f);
    }
    #pragma unroll
    for (int k = 0; k < 2; ++k) {
        wc0[k] = *(const f32x4*)(WcT + (size_t)r0*S + 4*(lane + 64*k));
        wc1[k] = *(const f32x4*)(WcT + (size_t)r1*S + 4*(lane + 64*k));
        ep[k] = (f32x4)(0.f); va[k] = (f32x4)(0.f);
    }
    if (attn_blk) {
        #pragma unroll
        for (int k = 0; k < 8; ++k)
            wa[k] = *(const f32x4*)(Wa_dec + (size_t)w*H + 4*(lane + 64*k));
        #pragma unroll
        for (int k = 0; k < 2; ++k) {
            ep[k] = *(const f32x4*)(enc_proj + (size_t)w*A + 4*(lane + 64*k));
            va[k] = *(const f32x4*)(v_a + 4*(lane + 64*k));
        }
    }
    const f32x4* hs4 = (const f32x4*)hs;
    const f32x4* ps4 = (const f32x4*)ps;
    const f32x4* es4 = (const f32x4*)es;

    for (int t = 0; t < S; ++t) {
        // prefetch this step's accx (L2 hit) so final publish isn't gated on it
        float ax0 = 0.f, ax1 = 0.f;
        if (lane == 0) {
            ax0 = accx[(size_t)t*H + r0];
            ax1 = accx[(size_t)t*H + r1];
        }

        // ---- A: stage h_{t-1} ----
        if (t == 0) {
            ((f32x4*)hs)[tid] = ((const f32x4*)(enc_states + (size_t)(S-1)*H))[tid];
        } else {
            f32x4 ca, cb;
            const float* hb = hexd + ((t-1)&1)*(1024*CH);
            poll2(hb + (2*tid)*CH, hb + (2*tid+1)*CH, t, ca, cb);
            hs[4*tid+0] = ca.x; hs[4*tid+1] = ca.y;
            hs[4*tid+2] = cb.x; hs[4*tid+3] = cb.y;
        }
        __syncthreads();                                   // sync1

        // ---- B: publish dec_proj ASAP, then heavy W_h dot ----
        if (attn_blk) {
            float aP = 0.f;
            #pragma unroll
            for (int k = 0; k < 8; ++k) {
                f32x4 hv = hs4[lane + 64*k];
                aP += wa[k].x*hv.x + wa[k].y*hv.y + wa[k].z*hv.z + wa[k].w*hv.w;
            }
            #pragma unroll
            for (int off = 32; off; off >>= 1) aP += __shfl_down(aP, off);
            if (lane == 0) st_chunk(dpex + (t&1)*(512*CH) + w*CH, aP, 0.f, t+1);
        }
        float aH0 = 0.f, aH1 = 0.f;
        #pragma unroll
        for (int k = 0; k < 8; ++k) {
            f32x4 hv = hs4[lane + 64*k];
            aH0 += wh0[k].x*hv.x + wh0[k].y*hv.y + wh0[k].z*hv.z + wh0[k].w*hv.w;
            aH1 += wh1[k].x*hv.x + wh1[k].y*hv.y + wh1[k].z*hv.z + wh1[k].w*hv.w;
        }
        #pragma unroll
        for (int off = 32; off; off >>= 1) { aH0 += __shfl_down(aH0, off); aH1 += __shfl_down(aH1, off); }

        // ---- C: attention blocks: dp -> e ----
        if (attn_blk) {
            f32x4 c = poll1(dpex + (t&1)*(512*CH) + tid*CH, t+1);
            ps[tid] = c.x;
            __syncthreads();                               // sync2 (attn blocks only; block-uniform)
            float e_ = 0.f;
            #pragma unroll
            for (int k = 0; k < 2; ++k) {
                f32x4 p = ps4[lane + 64*k];
                e_ += va[k].x*tanhf(ep[k].x + p.x) + va[k].y*tanhf(ep[k].y + p.y)
                    + va[k].z*tanhf(ep[k].z + p.z) + va[k].w*tanhf(ep[k].w + p.w);
            }
            #pragma unroll
            for (int off = 32; off; off >>= 1) e_ += __shfl_down(e_, off);
            if (lane == 0) st_chunk(eex + (t&1)*(512*CH) + w*CH, expf(e_), 0.f, t+1);
        }

        // ---- D: all blocks: poll e ----
        {
            f32x4 c = poll1(eex + (t&1)*(512*CH) + tid*CH, t+1);
            es[tid] = c.x;
        }
        __syncthreads();                                   // syncD

        // ---- E: Z, ctx, h_new ----
        float z = es[tid];
        #pragma unroll
        for (int off = 32; off; off >>= 1) z += __shfl_down(z, off);
        if (lane == 0) zred[wid] = z;
        __syncthreads();                                   // syncZ
        const float Z = zred[0]+zred[1]+zred[2]+zred[3]+zred[4]+zred[5]+zred[6]+zred[7];

        float c0 = 0.f, c1 = 0.f;
        #pragma unroll
        for (int k = 0; k < 2; ++k) {
            f32x4 ev = es4[lane + 64*k];
            c0 += wc0[k].x*ev.x + wc0[k].y*ev.y + wc0[k].z*ev.z + wc0[k].w*ev.w;
            c1 += wc1[k].x*ev.x + wc1[k].y*ev.y + wc1[k].z*ev.z + wc1[k].w*ev.w;
        }
        #pragma unroll
        for (int off = 32; off; off >>= 1) { c0 += __shfl_down(c0, off); c1 += __shfl_down(c1, off); }
        if (lane == 0) {
            const float Zi = 1.f / Z;
            float h0 = tanhf(ax0 + aH0 + c0*Zi);
            float h1 = tanhf(ax1 + aH1 + c1*Zi);
            h_dec[(size_t)t*H + r0] = h0; h_dec[(size_t)t*H + r1] = h1;
            st_chunk(hexd + (t&1)*(1024*CH) + w*CH, h0, h1, t+1);
        }
    }
}

extern "C" void kernel_launch(void* const* d_in, const int* in_sizes, int n_in,
                              void* d_out, int out_size, void* d_ws, size_t ws_size,
                              hipStream_t stream) {
    const float* x_enc  = (const float*)d_in[0];
    const float* x_dec  = (const float*)d_in[1];
    const float* W_enc  = (const float*)d_in[2];
    const float* b_enc  = (const float*)d_in[3];
    const float* Wa_enc = (const float*)d_in[4];
    const float* Wa_dec = (const float*)d_in[5];
    const float* v_a    = (const float*)d_in[6];
    const float* W_dec  = (const float*)d_in[7];
    const float* b_dec  = (const float*)d_in[8];
    const float* W_out  = (const float*)d_in[9];
    const float* b_out  = (const float*)d_in[10];
    float* out = (float*)d_out;

    float* ws         = (float*)d_ws;
    float* accx_enc   = ws;                          // S*H
    float* enc_states = accx_enc + (size_t)S*H;      // S*H
    float* enc_proj   = enc_states + (size_t)S*H;    // S*A
    float* WcT        = enc_proj + (size_t)S*A;      // H*S
    float* accx_dec   = WcT + (size_t)H*S;           // S*H
    float* h_dec      = accx_dec + (size_t)S*H;      // S*H
    float* hex_e      = h_dec + (size_t)S*H;         // 2*1024*CH = 131072
    float* hex_d      = hex_e + 2*1024*CH;           // 131072
    float* dp_ex      = hex_d + 2*1024*CH;           // 2*512*CH = 65536
    float* e_ex       = dp_ex + 2*512*CH;            // 65536
    const int n_ex = 2*1024*CH + 2*1024*CH + 2*512*CH + 2*512*CH;  // 393216 floats

    dim3 b256(256);

    init_ex<<<dim3((n_ex + 255)/256), b256, 0, stream>>>(hex_e, n_ex);

    // accx_enc = x_enc @ W_enc[:, :V].T + b_enc
    gemm_nt<<<dim3(H/64, S/64), b256, 0, stream>>>(x_enc, V, W_enc, V+H, accx_enc, H, b_enc, S, H, V);
    // accx_dec = x_dec @ W_dec[:, :V].T + b_dec
    gemm_nt<<<dim3(H/64, S/64), b256, 0, stream>>>(x_dec, V, W_dec, V+2*H, accx_dec, H, b_dec, S, H, V);

    // encoder scan (cooperative, persistent, payload-polling)
    {
        const float* We = W_enc; const float* ax = accx_enc; float* st = enc_states; float* hx = hex_e;
        void* args[] = { &We, &ax, &st, &hx };
        hipLaunchCooperativeKernel((void*)enc_scan, dim3(NBLK), dim3(NTHR), args, 0, stream);
    }

    // enc_proj = enc_states @ Wa_enc.T
    gemm_nt<<<dim3(A/64, S/64), b256, 0, stream>>>(enc_states, H, Wa_enc, H, enc_proj, A, nullptr, S, A, H);
    // WcT[i][s] = W_c[i]·enc_states[s]
    gemm_nt<<<dim3(S/64, H/64), b256, 0, stream>>>(W_dec + V, V+2*H, enc_states, H, WcT, S, nullptr, H, S, H);

    // decoder scan (cooperative, persistent, payload-polling)
    {
        const float* wa = Wa_dec; const float* wd = W_dec; const float* epj = enc_proj;
        const float* vv = v_a; const float* wc = WcT; const float* ax = accx_dec;
        const float* est = enc_states; float* hd = h_dec;
        float* hx = hex_d; float* dx = dp_ex; float* ex = e_ex;
        void* args[] = { &wa, &wd, &epj, &vv, &wc, &ax, &est, &hd, &hx, &dx, &ex };
        hipLaunchCooperativeKernel((void*)dec_scan, dim3(NBLK), dim3(NTHR), args, 0, stream);
    }

    // logits = h_dec @ W_out.T + b_out
    gemm_nt<<<dim3(V/64, S/64), b256, 0, stream>>>(h_dec, H, W_out, H, out, V, b_out, S, V, H);
}